// Round 14
// baseline (1086.850 us; speedup 1.0000x reference)
//
#include <hip/hip_runtime.h>
#include <cstdint>
#include <cstddef>

// ---------------------------------------------------------------------------
// GraphMathSolver: 4-layer MPNN on MI355X.
// Round 14: k_msg two-tile blocks (128 edges/block, grid 1250).
//   - tile1 y-gathers issued between dump-t0 and scan-t0 (latency hidden
//     under scan; acc regs dead there -> no VGPR peak growth)
//   - per-block setup amortized 2x; GEMM1 weights L1-hot for tile1
//   Everything else identical to round 13 (best: 544.6us).
// ---------------------------------------------------------------------------

typedef unsigned short u16;
typedef __attribute__((ext_vector_type(4))) float f32x4;
typedef __attribute__((ext_vector_type(8))) short bf16x8;
typedef __attribute__((ext_vector_type(4))) short s16x4;

constexpr int kN  = 10000;
constexpr int kE  = 160000;
constexpr int kB  = 64;
constexpr int kH  = 256;
constexpr int kL  = 4;
constexpr int kC  = 10;
constexpr float kEps = 1e-5f;

struct __align__(16) F4 { float v[4]; };
__device__ __forceinline__ F4 ldF4(const float* p) { return *reinterpret_cast<const F4*>(p); }

__device__ __forceinline__ u16 f2bf(float f) {
    unsigned u = __builtin_bit_cast(unsigned, f);
    return (u16)((u + 0x7fffu + ((u >> 16) & 1u)) >> 16);
}
__device__ __forceinline__ float bf2f(u16 h) {
    return __builtin_bit_cast(float, (unsigned)h << 16);
}
__device__ __forceinline__ unsigned cvtpk(float lo, float hi) {
    unsigned r;
    asm("v_cvt_pk_bf16_f32 %0, %1, %2" : "=v"(r) : "v"(lo), "v"(hi));
    return r;
}

// ---- async global->LDS DMA, 16B per lane ----------------------------------
typedef __attribute__((address_space(1))) void GV;
typedef __attribute__((address_space(3))) void LV;
__device__ __forceinline__ void gl_lds16(const void* g, void* l) {
    __builtin_amdgcn_global_load_lds((GV*)g, (LV*)l, 16, 0, 0);
}
__device__ __forceinline__ void dma_w16k(const u16* __restrict__ Wc, char* lds, int tid) {
    const int w = tid >> 6, lane = tid & 63;
    char* lb = lds + w * 4096;
    const char* gb = (const char*)Wc + w * 4096 + lane * 16;
    #pragma unroll
    for (int i = 0; i < 4; ++i) gl_lds16(gb + i * 1024, lb + i * 1024);
}

// direct global fragment read from swizzled-linear chunk layout [n=256][k=32]
__device__ __forceinline__ bf16x8 g_frag(const u16* __restrict__ g, int n, int kg) {
    return *reinterpret_cast<const bf16x8*>(g + n * 32 + ((kg ^ ((n >> 1) & 3)) << 3));
}
// LDS fragment readers (XOR-swizzled)
__device__ __forceinline__ bf16x8 rdfrag(const char* lds, int n, int kg) {
    return *reinterpret_cast<const bf16x8*>(lds + n * 64 + ((kg ^ ((n >> 1) & 3)) << 4));
}
__device__ __forceinline__ bf16x8 rdH(const char* H, int row, int kbyte) {
    return *reinterpret_cast<const bf16x8*>(H + row * 512 + (kbyte ^ ((row & 7) << 4)));
}

// ---------------- int64/int32 index handling -------------------------------
__global__ void k_detect_i64(const unsigned* __restrict__ w, int* __restrict__ flag) {
    if (threadIdx.x == 0 && blockIdx.x == 0) {
        int is64 = 1;
        for (int i = 0; i < 64; ++i)
            if (w[2*i + 1] != 0u) { is64 = 0; break; }
        *flag = is64;
    }
}
__global__ void k_cvt_idx(const unsigned* __restrict__ w, const int* __restrict__ flag,
                          int* __restrict__ out, int n) {
    int i = blockIdx.x * 256 + threadIdx.x;
    if (i < n) out[i] = (*flag) ? (int)w[2*i] : (int)w[i];
}

// ---------------- counting sort of edges by dst ----------------------------
__global__ __launch_bounds__(256) void k_hist(const int* __restrict__ dst,
                                              int* __restrict__ cnt) {
    int e = blockIdx.x * 256 + threadIdx.x;
    if (e < kE) atomicAdd(&cnt[dst[e]], 1);
}
__global__ __launch_bounds__(256) void k_scan(const int* __restrict__ cnt,
                                              int* __restrict__ cur) {
    __shared__ int part[256];
    const int t = threadIdx.x;
    const int per = (kN + 255) / 256;
    int s = 0;
    for (int i = 0; i < per; ++i) {
        int idx = t * per + i;
        if (idx < kN) s += cnt[idx];
    }
    int own = s;
    part[t] = s; __syncthreads();
    for (int off = 1; off < 256; off <<= 1) {
        int v = (t >= off) ? part[t - off] : 0;
        __syncthreads();
        part[t] += v;
        __syncthreads();
    }
    int run = part[t] - own;
    for (int i = 0; i < per; ++i) {
        int idx = t * per + i;
        if (idx < kN) { cur[idx] = run; run += cnt[idx]; }
    }
}
__global__ __launch_bounds__(256) void k_scatter(
    const int* __restrict__ src, const int* __restrict__ dst,
    int* __restrict__ cur, int* __restrict__ rank,
    int* __restrict__ ssorted, int* __restrict__ dsorted) {
    int e = blockIdx.x * 256 + threadIdx.x;
    if (e < kE) {
        int d = dst[e];
        int p = atomicAdd(&cur[d], 1);
        rank[e] = p;
        ssorted[p] = src[e];
        dsorted[p] = d;
    }
}

// ---- weight prep: fp32 [L][K][256] -> bf16 swizzled-linear [L][kc][n][32] --
__global__ __launch_bounds__(256) void k_prep_w(
    const float* __restrict__ mW1, const float* __restrict__ mW2,
    const float* __restrict__ uW1, const float* __restrict__ uW2,
    u16* __restrict__ tm1, u16* __restrict__ tm2,
    u16* __restrict__ tu1, u16* __restrict__ tu2)
{
    int idx = blockIdx.x * 256 + threadIdx.x;
    const int S1 = kL * 768 * 256;
    const int S2 = S1 + kL * 256 * 256;
    const int S3 = S2 + kL * 512 * 256;
    const int S4 = S3 + kL * 256 * 256;
    const float* src; u16* dst; int K, r;
    if (idx < S1)      { src = mW1; dst = tm1; K = 768; r = idx; }
    else if (idx < S2) { src = mW2; dst = tm2; K = 256; r = idx - S1; }
    else if (idx < S3) { src = uW1; dst = tu1; K = 512; r = idx - S2; }
    else if (idx < S4) { src = uW2; dst = tu2; K = 256; r = idx - S3; }
    else return;
    int per = K * 256;
    int layer = r / per, rr = r - layer * per;
    int k = rr >> 8, n = rr & 255;
    int kc = k >> 5, kg = (k >> 3) & 3, e = k & 7;
    dst[(size_t)layer * per + (size_t)kc * 8192 + n * 32 + ((kg ^ ((n >> 1) & 3)) << 3) + e]
        = f2bf(src[(size_t)layer * per + rr]);
}

// ---- ef prep: LINEAR read, rank-scattered write into block chunk layout ----
__global__ __launch_bounds__(256) void k_prep_ef(
    const float* __restrict__ ef, const int* __restrict__ rank,
    u16* __restrict__ efs)
{
    int idx = blockIdx.x * 256 + threadIdx.x;
    if (idx >= kE * 64) return;
    int e = idx >> 6, k = idx & 63;
    float v = ef[idx];                      // coalesced linear read
    int p = rank[e];
    int row = p & 63, blk = p >> 6;
    int kc = k >> 5, kg = (k >> 3) & 3, ee = k & 7;
    efs[(size_t)blk * 4096 + kc * 2048 + row * 32
        + ((kg ^ ((row >> 1) & 3)) << 3) + ee] = f2bf(v);
}

// ---- M[l] = We @ W1c[l] (64x256), b1'[l] = b1[l] + be @ W1c[l] -------------
__global__ __launch_bounds__(256) void k_prep_m(
    const float* __restrict__ eW, const float* __restrict__ eb,
    const float* __restrict__ mW1, const float* __restrict__ mb1,
    u16* __restrict__ tmc, float* __restrict__ b1p)
{
    __shared__ float sWe[16 * 256];
    const int l = blockIdx.x, rq = blockIdx.y, t = threadIdx.x;
    const int r0 = rq * 16;
    #pragma unroll
    for (int i = 0; i < 16; ++i) sWe[i * 256 + t] = eW[(size_t)(r0 + i) * 256 + t];
    __syncthreads();
    const float* W1c = mW1 + (size_t)l * 768 * 256 + (size_t)512 * 256;
    float m[16];
    #pragma unroll
    for (int r = 0; r < 16; ++r) m[r] = 0.f;
    float bp = (rq == 0) ? mb1[l * 256 + t] : 0.f;
    for (int j = 0; j < 256; ++j) {
        float wv = W1c[(size_t)j * 256 + t];
        if (rq == 0) bp = fmaf(eb[j], wv, bp);
        #pragma unroll
        for (int r = 0; r < 16; ++r) m[r] = fmaf(sWe[r * 256 + j], wv, m[r]);
    }
    if (rq == 0) b1p[l * 256 + t] = bp;
    #pragma unroll
    for (int r = 0; r < 16; ++r) {
        int k = r0 + r;
        int kc = k >> 5, kg = (k >> 3) & 3, e = k & 7;
        tmc[(size_t)l * 16384 + (size_t)kc * 8192 + t * 32
            + ((kg ^ ((t >> 1) & 3)) << 3) + e] = f2bf(m[r]);
    }
}

// ---------------- node encoder (scalar fp32, small) ------------------------
__global__ __launch_bounds__(256) void k_encode_nodes(
    const float* __restrict__ nf, const float* __restrict__ W,
    const float* __restrict__ b, float* __restrict__ x, u16* __restrict__ x_bf)
{
    __shared__ float s_nf[4 * 128];
    const int n0 = blockIdx.x * 4;
    const int tid = threadIdx.x;
    reinterpret_cast<float2*>(s_nf)[tid] =
        reinterpret_cast<const float2*>(nf + (size_t)n0 * 128)[tid];
    __syncthreads();
    float acc[4] = {0.f, 0.f, 0.f, 0.f};
    for (int k = 0; k < 128; ++k) {
        float w = W[k * kH + tid];
        #pragma unroll
        for (int r = 0; r < 4; ++r) acc[r] = fmaf(s_nf[r * 128 + k], w, acc[r]);
    }
    float bias = b[tid];
    #pragma unroll
    for (int r = 0; r < 4; ++r) {
        float o = acc[r] + bias;
        x[(size_t)(n0 + r) * kH + tid] = o;
        x_bf[(size_t)(n0 + r) * kH + tid] = f2bf(o);
    }
}

// ---------------- per-node pre-GEMM: y_{a,b,c}, dbuf single-barrier --------
__global__ __launch_bounds__(256, 3) void k_node_pre(
    const u16* __restrict__ x_bf, const u16* __restrict__ Wtm1,
    const u16* __restrict__ Wtu1,
    u16* __restrict__ y_a, u16* __restrict__ y_b, u16* __restrict__ y_c)
{
    __shared__ char sWt[2][16384];
    __shared__ char sA[2][4096];
    const int tid = threadIdx.x;
    const int n0 = blockIdx.x * 64;
    const int half = blockIdx.y;
    const u16* Wt = (half == 2) ? Wtu1 : Wtm1 + (size_t)half * 8 * 8192;
    u16* y = (half == 0) ? y_a : (half == 1 ? y_b : y_c);
    const int w = tid >> 6, lane = tid & 63;
    const int lr = lane & 15, lg = lane >> 4;
    const int srow = tid >> 2, skg = tid & 3;
    const int kg_src = skg ^ ((srow >> 1) & 3);
    int gnode = n0 + srow; if (gnode >= kN) gnode = kN - 1;

    f32x4 acc[4][4];
    #pragma unroll
    for (int i = 0; i < 4; ++i)
        #pragma unroll
        for (int j = 0; j < 4; ++j) acc[i][j] = (f32x4){0.f, 0.f, 0.f, 0.f};

    dma_w16k(Wt, sWt[0], tid);
    gl_lds16(x_bf + (size_t)gnode * kH + kg_src * 8, sA[0] + w * 1024);
    __syncthreads();

    for (int kc = 0; kc < 8; ++kc) {
        const int cur = kc & 1, nxt = cur ^ 1;
        if (kc < 7) {
            dma_w16k(Wt + (size_t)(kc + 1) * 8192, sWt[nxt], tid);
            gl_lds16(x_bf + (size_t)gnode * kH + (kc + 1) * 32 + kg_src * 8,
                     sA[nxt] + w * 1024);
        }
        bf16x8 af[4], bfm[4];
        #pragma unroll
        for (int i = 0; i < 4; ++i) af[i] = rdfrag(sWt[cur], w * 64 + i * 16 + lr, lg);
        #pragma unroll
        for (int j = 0; j < 4; ++j) bfm[j] = rdfrag(sA[cur], j * 16 + lr, lg);
        #pragma unroll
        for (int i = 0; i < 4; ++i)
            #pragma unroll
            for (int j = 0; j < 4; ++j)
                acc[i][j] = __builtin_amdgcn_mfma_f32_16x16x32_bf16(af[i], bfm[j], acc[i][j], 0, 0, 0);
        __syncthreads();
    }
    #pragma unroll
    for (int i = 0; i < 4; ++i) {
        const int hc0 = w * 64 + i * 16 + lg * 4;
        #pragma unroll
        for (int j = 0; j < 4; ++j) {
            const int node = n0 + j * 16 + lr;
            if (node < kN) {
                uint2 o;
                o.x = cvtpk(acc[i][j][0], acc[i][j][1]);
                o.y = cvtpk(acc[i][j][2], acc[i][j][3]);
                *reinterpret_cast<uint2*>(y + (size_t)node * kH + hc0) = o;
            }
        }
    }
}

// ---------------- edge message MLP + segmented scatter (two tiles) ---------
// Block handles 128 sorted edges as two 64-edge tiles sharing one 32KB sBuf.
// tile1 y-gathers issued between dump-t0 and scan-t0 (hidden under scan).
__global__ __launch_bounds__(256, 4) void k_msg(
    const u16* __restrict__ efs,
    const int* __restrict__ ssorted, const int* __restrict__ dsorted,
    const u16* __restrict__ y_a, const u16* __restrict__ y_b,
    const u16* __restrict__ Wtm, const float* __restrict__ b1p,
    const u16* __restrict__ Wt2, const float* __restrict__ b2,
    float* __restrict__ agg)
{
    __shared__ __align__(16) char sBuf[32768]; // h1 -> msg [64][256] bf16 swz

    const int tid = threadIdx.x;
    const int nwg = gridDim.x;
    const int q8 = nwg >> 3, r8 = nwg & 7;
    const int xcd = blockIdx.x & 7, sub = blockIdx.x >> 3;
    const int bid = (xcd < r8 ? xcd * (q8 + 1) : r8 * (q8 + 1) + (xcd - r8) * q8) + sub;
    const int e0 = bid * 128;

    const int w = tid >> 6, lane = tid & 63;
    const int lr = lane & 15, lg = lane >> 4;

    // ---- tile0 dst mask + y-gathers ----
    const int myDst0 = dsorted[e0 + lane];
    const unsigned long long bm0 = __ballot(lane == 63 || myDst0 != __shfl_down(myDst0, 1));
    const unsigned m0lo = __builtin_amdgcn_readfirstlane((unsigned)(bm0 & 0xffffffffu));
    const unsigned m0hi = __builtin_amdgcn_readfirstlane((unsigned)(bm0 >> 32));
    uint2 ya[4][4], yb[4][4];
    #pragma unroll
    for (int j = 0; j < 4; ++j) {
        const int es = ssorted[e0 + j * 16 + lr];
        const int ed = __shfl(myDst0, j * 16 + lr);
        const u16* pa = y_a + (size_t)es * kH;
        const u16* pb = y_b + (size_t)ed * kH;
        #pragma unroll
        for (int i = 0; i < 4; ++i) {
            const int hc0 = w * 64 + i * 16 + lg * 4;
            ya[j][i] = *reinterpret_cast<const uint2*>(pa + hc0);
            yb[j][i] = *reinterpret_cast<const uint2*>(pb + hc0);
        }
    }
    // tile1 mask (cheap; gathers deferred)
    const int myDst1 = dsorted[e0 + 64 + lane];
    const unsigned long long bm1 = __ballot(lane == 63 || myDst1 != __shfl_down(myDst1, 1));
    const unsigned m1lo = __builtin_amdgcn_readfirstlane((unsigned)(bm1 & 0xffffffffu));
    const unsigned m1hi = __builtin_amdgcn_readfirstlane((unsigned)(bm1 >> 32));

    f32x4 acc[4][4];
    #pragma unroll
    for (int i = 0; i < 4; ++i)
        #pragma unroll
        for (int j = 0; j < 4; ++j) acc[i][j] = (f32x4){0.f, 0.f, 0.f, 0.f};

    // ================= TILE 0 =================
    // ---- GEMM1 (swapped): pe^T = M^T @ ef^T, K = 64 ----
    #pragma unroll
    for (int kc = 0; kc < 2; ++kc) {
        const u16* efc = efs + (size_t)bid * 8192 + kc * 2048;
        bf16x8 af[4], bfm[4];
        #pragma unroll
        for (int i = 0; i < 4; ++i) af[i] = g_frag(Wtm + kc * 8192, w * 64 + i * 16 + lr, lg);
        #pragma unroll
        for (int j = 0; j < 4; ++j) {
            int row = j * 16 + lr;
            bfm[j] = *reinterpret_cast<const bf16x8*>(
                efc + row * 32 + ((lg ^ ((row >> 1) & 3)) << 3));
        }
        #pragma unroll
        for (int i = 0; i < 4; ++i)
            #pragma unroll
            for (int j = 0; j < 4; ++j)
                acc[i][j] = __builtin_amdgcn_mfma_f32_16x16x32_bf16(af[i], bfm[j], acc[i][j], 0, 0, 0);
    }
    // ---- epilogue 1: h1 -> sBuf ----
    #pragma unroll
    for (int j = 0; j < 4; ++j) {
        const int edge = j * 16 + lr;
        #pragma unroll
        for (int i = 0; i < 4; ++i) {
            const int hc0 = w * 64 + i * 16 + lg * 4;
            const F4 bb = ldF4(b1p + hc0);
            float s0 = __builtin_bit_cast(float, ya[j][i].x << 16) + __builtin_bit_cast(float, yb[j][i].x << 16);
            float s1 = __builtin_bit_cast(float, ya[j][i].x & 0xffff0000u) + __builtin_bit_cast(float, yb[j][i].x & 0xffff0000u);
            float s2 = __builtin_bit_cast(float, ya[j][i].y << 16) + __builtin_bit_cast(float, yb[j][i].y << 16);
            float s3 = __builtin_bit_cast(float, ya[j][i].y & 0xffff0000u) + __builtin_bit_cast(float, yb[j][i].y & 0xffff0000u);
            float h0 = acc[i][j][0] + bb.v[0] + s0; h0 = h0 > 0.f ? h0 : 0.f;
            float h1 = acc[i][j][1] + bb.v[1] + s1; h1 = h1 > 0.f ? h1 : 0.f;
            float h2 = acc[i][j][2] + bb.v[2] + s2; h2 = h2 > 0.f ? h2 : 0.f;
            float h3 = acc[i][j][3] + bb.v[3] + s3; h3 = h3 > 0.f ? h3 : 0.f;
            uint2 o; o.x = cvtpk(h0, h1); o.y = cvtpk(h2, h3);
            int byte = edge * 512 + hc0 * 2;
            *reinterpret_cast<uint2*>(sBuf + (byte ^ ((edge & 7) << 4))) = o;
            acc[i][j] = (f32x4){0.f, 0.f, 0.f, 0.f};
        }
    }
    __syncthreads();

    // ---- GEMM2: msg = h1 @ W2, K = 256 ----
    #pragma unroll 2
    for (int kc = 0; kc < 8; ++kc) {
        bf16x8 af2[4], bf2[4];
        #pragma unroll
        for (int i = 0; i < 4; ++i) af2[i] = rdH(sBuf, i * 16 + lr, kc * 64 + lg * 16);
        #pragma unroll
        for (int j = 0; j < 4; ++j) bf2[j] = g_frag(Wt2 + kc * 8192, w * 64 + j * 16 + lr, lg);
        #pragma unroll
        for (int i = 0; i < 4; ++i)
            #pragma unroll
            for (int j = 0; j < 4; ++j)
                acc[i][j] = __builtin_amdgcn_mfma_f32_16x16x32_bf16(af2[i], bf2[j], acc[i][j], 0, 0, 0);
    }
    __syncthreads();

    // ---- dump msg t0 ----
    #pragma unroll
    for (int j = 0; j < 4; ++j) {
        const int oc = w * 64 + j * 16 + lr;
        const float b2v = b2[oc];
        #pragma unroll
        for (int i = 0; i < 4; ++i) {
            unsigned p01 = cvtpk(acc[i][j][0] + b2v, acc[i][j][1] + b2v);
            unsigned p23 = cvtpk(acc[i][j][2] + b2v, acc[i][j][3] + b2v);
            int eb0 = i * 16 + lg * 4;
            *reinterpret_cast<u16*>(sBuf + (((eb0 + 0) * 512 + oc * 2) ^ (((eb0 + 0) & 7) << 4))) = (u16)p01;
            *reinterpret_cast<u16*>(sBuf + (((eb0 + 1) * 512 + oc * 2) ^ (((eb0 + 1) & 7) << 4))) = (u16)(p01 >> 16);
            *reinterpret_cast<u16*>(sBuf + (((eb0 + 2) * 512 + oc * 2) ^ (((eb0 + 2) & 7) << 4))) = (u16)p23;
            *reinterpret_cast<u16*>(sBuf + (((eb0 + 3) * 512 + oc * 2) ^ (((eb0 + 3) & 7) << 4))) = (u16)(p23 >> 16);
        }
    }
    __syncthreads();

    // ---- tile1 y-gathers issued NOW (latency hides under scan t0) ----
    uint2 ya1[4][4], yb1[4][4];
    #pragma unroll
    for (int j = 0; j < 4; ++j) {
        const int es = ssorted[e0 + 64 + j * 16 + lr];
        const int ed = __shfl(myDst1, j * 16 + lr);
        const u16* pa = y_a + (size_t)es * kH;
        const u16* pb = y_b + (size_t)ed * kH;
        #pragma unroll
        for (int i = 0; i < 4; ++i) {
            const int hc0 = w * 64 + i * 16 + lg * 4;
            ya1[j][i] = *reinterpret_cast<const uint2*>(pa + hc0);
            yb1[j][i] = *reinterpret_cast<const uint2*>(pb + hc0);
        }
    }

    // ---- scan t0 ----
    {
        const int col = tid;
        float run = 0.f;
        #pragma unroll
        for (int e = 0; e < 64; ++e) {
            int byte = e * 512 + col * 2;
            run += bf2f(*reinterpret_cast<const u16*>(sBuf + (byte ^ ((e & 7) << 4))));
            unsigned mm = (e < 32) ? m0lo : m0hi;
            if ((mm >> (e & 31)) & 1u) {
                int d = __shfl(myDst0, e);
                unsafeAtomicAdd(agg + (size_t)d * kH + col, run);
                run = 0.f;
            }
        }
    }
    __syncthreads();   // sBuf reuse fence

    // ================= TILE 1 =================
    #pragma unroll
    for (int i = 0; i < 4; ++i)
        #pragma unroll
        for (int j = 0; j < 4; ++j) acc[i][j] = (f32x4){0.f, 0.f, 0.f, 0.f};

    #pragma unroll
    for (int kc = 0; kc < 2; ++kc) {
        const u16* efc = efs + (size_t)bid * 8192 + 4096 + kc * 2048;
        bf16x8 af[4], bfm[4];
        #pragma unroll
        for (int i = 0; i < 4; ++i) af[i] = g_frag(Wtm + kc * 8192, w * 64 + i * 16 + lr, lg);
        #pragma unroll
        for (int j = 0; j < 4; ++j) {
            int row = j * 16 + lr;
            bfm[j] = *reinterpret_cast<const bf16x8*>(
                efc + row * 32 + ((lg ^ ((row >> 1) & 3)) << 3));
        }
        #pragma unroll
        for (int i = 0; i < 4; ++i)
            #pragma unroll
            for (int j = 0; j < 4; ++j)
                acc[i][j] = __builtin_amdgcn_mfma_f32_16x16x32_bf16(af[i], bfm[j], acc[i][j], 0, 0, 0);
    }
    #pragma unroll
    for (int j = 0; j < 4; ++j) {
        const int edge = j * 16 + lr;
        #pragma unroll
        for (int i = 0; i < 4; ++i) {
            const int hc0 = w * 64 + i * 16 + lg * 4;
            const F4 bb = ldF4(b1p + hc0);
            float s0 = __builtin_bit_cast(float, ya1[j][i].x << 16) + __builtin_bit_cast(float, yb1[j][i].x << 16);
            float s1 = __builtin_bit_cast(float, ya1[j][i].x & 0xffff0000u) + __builtin_bit_cast(float, yb1[j][i].x & 0xffff0000u);
            float s2 = __builtin_bit_cast(float, ya1[j][i].y << 16) + __builtin_bit_cast(float, yb1[j][i].y << 16);
            float s3 = __builtin_bit_cast(float, ya1[j][i].y & 0xffff0000u) + __builtin_bit_cast(float, yb1[j][i].y & 0xffff0000u);
            float h0 = acc[i][j][0] + bb.v[0] + s0; h0 = h0 > 0.f ? h0 : 0.f;
            float h1 = acc[i][j][1] + bb.v[1] + s1; h1 = h1 > 0.f ? h1 : 0.f;
            float h2 = acc[i][j][2] + bb.v[2] + s2; h2 = h2 > 0.f ? h2 : 0.f;
            float h3 = acc[i][j][3] + bb.v[3] + s3; h3 = h3 > 0.f ? h3 : 0.f;
            uint2 o; o.x = cvtpk(h0, h1); o.y = cvtpk(h2, h3);
            int byte = edge * 512 + hc0 * 2;
            *reinterpret_cast<uint2*>(sBuf + (byte ^ ((edge & 7) << 4))) = o;
            acc[i][j] = (f32x4){0.f, 0.f, 0.f, 0.f};
        }
    }
    __syncthreads();

    #pragma unroll 2
    for (int kc = 0; kc < 8; ++kc) {
        bf16x8 af2[4], bf2[4];
        #pragma unroll
        for (int i = 0; i < 4; ++i) af2[i] = rdH(sBuf, i * 16 + lr, kc * 64 + lg * 16);
        #pragma unroll
        for (int j = 0; j < 4; ++j) bf2[j] = g_frag(Wt2 + kc * 8192, w * 64 + j * 16 + lr, lg);
        #pragma unroll
        for (int i = 0; i < 4; ++i)
            #pragma unroll
            for (int j = 0; j < 4; ++j)
                acc[i][j] = __builtin_amdgcn_mfma_f32_16x16x32_bf16(af2[i], bf2[j], acc[i][j], 0, 0, 0);
    }
    __syncthreads();

    #pragma unroll
    for (int j = 0; j < 4; ++j) {
        const int oc = w * 64 + j * 16 + lr;
        const float b2v = b2[oc];
        #pragma unroll
        for (int i = 0; i < 4; ++i) {
            unsigned p01 = cvtpk(acc[i][j][0] + b2v, acc[i][j][1] + b2v);
            unsigned p23 = cvtpk(acc[i][j][2] + b2v, acc[i][j][3] + b2v);
            int eb0 = i * 16 + lg * 4;
            *reinterpret_cast<u16*>(sBuf + (((eb0 + 0) * 512 + oc * 2) ^ (((eb0 + 0) & 7) << 4))) = (u16)p01;
            *reinterpret_cast<u16*>(sBuf + (((eb0 + 1) * 512 + oc * 2) ^ (((eb0 + 1) & 7) << 4))) = (u16)(p01 >> 16);
            *reinterpret_cast<u16*>(sBuf + (((eb0 + 2) * 512 + oc * 2) ^ (((eb0 + 2) & 7) << 4))) = (u16)p23;
            *reinterpret_cast<u16*>(sBuf + (((eb0 + 3) * 512 + oc * 2) ^ (((eb0 + 3) & 7) << 4))) = (u16)(p23 >> 16);
        }
    }
    __syncthreads();

    {
        const int col = tid;
        float run = 0.f;
        #pragma unroll
        for (int e = 0; e < 64; ++e) {
            int byte = e * 512 + col * 2;
            run += bf2f(*reinterpret_cast<const u16*>(sBuf + (byte ^ ((e & 7) << 4))));
            unsigned mm = (e < 32) ? m1lo : m1hi;
            if ((mm >> (e & 31)) & 1u) {
                int d = __shfl(myDst1, e);
                unsafeAtomicAdd(agg + (size_t)d * kH + col, run);
                run = 0.f;
            }
        }
    }
}

// ---------------- node update: 32-row tiles, agg-only GEMM1 + y_c ----------
__global__ __launch_bounds__(256, 3) void k_upd(
    float* __restrict__ x, u16* __restrict__ x_bf,
    float* __restrict__ agg,
    const u16* __restrict__ Wt1b, const float* __restrict__ b1,
    const u16* __restrict__ Wt2, const float* __restrict__ b2,
    const float* __restrict__ lng, const float* __restrict__ lnb,
    const u16* __restrict__ y_c)
{
    __shared__ char sWt[2][16384];
    __shared__ char sA[2][2048];   // agg tile [32 rows][32 k] bf16 swz
    __shared__ char sH[16384];     // h tile [32 rows][256] bf16 swz

    const int tid = threadIdx.x;
    const int n0 = blockIdx.x * 32;
    const int w = tid >> 6, lane = tid & 63;
    const int lr = lane & 15, lg = lane >> 4;
    const int srow = tid >> 2, skg = tid & 3;
    int gnode = n0 + (srow & 31); if (gnode >= kN) gnode = kN - 1;
    const bool stg = tid < 128;

    // hoisted y_c gathers (hide latency under GEMM1)
    uint2 ycv[4][2];
    #pragma unroll
    for (int i = 0; i < 4; ++i) {
        const int hc0 = w * 64 + i * 16 + lg * 4;
        #pragma unroll
        for (int j = 0; j < 2; ++j) {
            int ncl = n0 + j * 16 + lr; if (ncl >= kN) ncl = kN - 1;
            ycv[i][j] = *reinterpret_cast<const uint2*>(y_c + (size_t)ncl * kH + hc0);
        }
    }

    f32x4 acc[4][4];
    #pragma unroll
    for (int i = 0; i < 4; ++i)
        #pragma unroll
        for (int j = 0; j < 4; ++j) acc[i][j] = (f32x4){0.f, 0.f, 0.f, 0.f};

    dma_w16k(Wt1b, sWt[0], tid);
    if (stg) {
        const float* ap = agg + (size_t)gnode * kH + skg * 8;
        F4 a0 = ldF4(ap), a1 = ldF4(ap + 4);
        int4 bv;
        bv.x = (int)cvtpk(a0.v[0], a0.v[1]);
        bv.y = (int)cvtpk(a0.v[2], a0.v[3]);
        bv.z = (int)cvtpk(a1.v[0], a1.v[1]);
        bv.w = (int)cvtpk(a1.v[2], a1.v[3]);
        *reinterpret_cast<int4*>(sA[0] + srow * 64 + ((skg ^ ((srow >> 1) & 3)) << 4)) = bv;
    }
    __syncthreads();

    // ---- GEMM1 (swapped): h^T = uW1b^T @ agg^T, K = 256 = 8 chunks ----
    for (int kc = 0; kc < 8; ++kc) {
        const int cur = kc & 1, nxt = cur ^ 1;
        bool pf = false; F4 a0, a1;
        if (kc < 7) {
            dma_w16k(Wt1b + (size_t)(kc + 1) * 8192, sWt[nxt], tid);
            if (stg) {
                const float* ap = agg + (size_t)gnode * kH + (kc + 1) * 32 + skg * 8;
                a0 = ldF4(ap); a1 = ldF4(ap + 4); pf = true;
            }
        } else {
            dma_w16k(Wt2, sWt[nxt], tid);
        }
        bf16x8 af[4], bfm[2];
        #pragma unroll
        for (int i = 0; i < 4; ++i) af[i] = rdfrag(sWt[cur], w * 64 + i * 16 + lr, lg);
        #pragma unroll
        for (int j = 0; j < 2; ++j) bfm[j] = rdfrag(sA[cur], j * 16 + lr, lg);
        #pragma unroll
        for (int i = 0; i < 4; ++i)
            #pragma unroll
            for (int j = 0; j < 2; ++j)
                acc[i][j] = __builtin_amdgcn_mfma_f32_16x16x32_bf16(af[i], bfm[j], acc[i][j], 0, 0, 0);
        if (pf) {
            int4 bv;
            bv.x = (int)cvtpk(a0.v[0], a0.v[1]);
            bv.y = (int)cvtpk(a0.v[2], a0.v[3]);
            bv.z = (int)cvtpk(a1.v[0], a1.v[1]);
            bv.w = (int)cvtpk(a1.v[2], a1.v[3]);
            *reinterpret_cast<int4*>(sA[nxt] + srow * 64 + ((skg ^ ((srow >> 1) & 3)) << 4)) = bv;
        }
        __syncthreads();
    }

    // ---- epilogue 1: h = relu(acc + b1 + y_c[node]) -> sH ----
    #pragma unroll
    for (int i = 0; i < 4; ++i) {
        const int hc0 = w * 64 + i * 16 + lg * 4;
        const F4 bb = ldF4(b1 + hc0);
        #pragma unroll
        for (int j = 0; j < 2; ++j) {
            const int row = j * 16 + lr;
            float s0 = __builtin_bit_cast(float, ycv[i][j].x << 16);
            float s1 = __builtin_bit_cast(float, ycv[i][j].x & 0xffff0000u);
            float s2 = __builtin_bit_cast(float, ycv[i][j].y << 16);
            float s3 = __builtin_bit_cast(float, ycv[i][j].y & 0xffff0000u);
            float h0 = acc[i][j][0] + bb.v[0] + s0; h0 = h0 > 0.f ? h0 : 0.f;
            float h1 = acc[i][j][1] + bb.v[1] + s1; h1 = h1 > 0.f ? h1 : 0.f;
            float h2 = acc[i][j][2] + bb.v[2] + s2; h2 = h2 > 0.f ? h2 : 0.f;
            float h3 = acc[i][j][3] + bb.v[3] + s3; h3 = h3 > 0.f ? h3 : 0.f;
            uint2 o; o.x = cvtpk(h0, h1); o.y = cvtpk(h2, h3);
            int byte = row * 512 + hc0 * 2;
            *reinterpret_cast<uint2*>(sH + (byte ^ ((row & 7) << 4))) = o;
            acc[i][j] = (f32x4){0.f, 0.f, 0.f, 0.f};
        }
    }
    __syncthreads();

    // zero this block's agg rows for the next layer (all reads done)
    {
        float4 z = make_float4(0.f, 0.f, 0.f, 0.f);
        float4* bp = reinterpret_cast<float4*>(agg + (size_t)n0 * kH);
        #pragma unroll
        for (int i = 0; i < 8; ++i) {
            int idx = i * 256 + tid;
            int row = idx >> 6;
            if (n0 + row < kN) bp[idx] = z;
        }
    }

    // ---- GEMM2 (normal): upd = h @ uW2, K = 256 = 8 chunks ----
    for (int kc = 0; kc < 8; ++kc) {
        const int cur = kc & 1, nxt = cur ^ 1;
        if (kc < 7) dma_w16k(Wt2 + (size_t)(kc + 1) * 8192, sWt[nxt], tid);
        bf16x8 af2[2], bf2[4];
        #pragma unroll
        for (int i = 0; i < 2; ++i) af2[i] = rdH(sH, i * 16 + lr, kc * 64 + lg * 16);
        #pragma unroll
        for (int j = 0; j < 4; ++j) bf2[j] = rdfrag(sWt[cur], w * 64 + j * 16 + lr, lg);
        #pragma unroll
        for (int i = 0; i < 2; ++i)
            #pragma unroll
            for (int j = 0; j < 4; ++j)
                acc[i][j] = __builtin_amdgcn_mfma_f32_16x16x32_bf16(af2[i], bf2[j], acc[i][j], 0, 0, 0);
        __syncthreads();
    }

    // ---- epilogue 2: + b2 + x (residual), LayerNorm over 32 nodes ----
    float b2v[4], gv[4], bvn[4];
    #pragma unroll
    for (int j = 0; j < 4; ++j) {
        int oc = w * 64 + j * 16 + lr;
        b2v[j] = b2[oc]; gv[j] = lng[oc]; bvn[j] = lnb[oc];
    }
    #pragma unroll
    for (int i = 0; i < 2; ++i)
        #pragma unroll
        for (int j = 0; j < 4; ++j) {
            int oc = w * 64 + j * 16 + lr;
            #pragma unroll
            for (int q = 0; q < 4; ++q) {
                int node = n0 + i * 16 + lg * 4 + q;
                int ncl = node < kN ? node : kN - 1;
                acc[i][j][q] += b2v[j] + x[(size_t)ncl * kH + oc];
            }
        }

    float (*red)[32][2] = reinterpret_cast<float(*)[32][2]>(sA[0]);
    float2* mstd = reinterpret_cast<float2*>((char*)sA[0] + 1024);
    #pragma unroll
    for (int i = 0; i < 2; ++i)
        #pragma unroll
        for (int q = 0; q < 4; ++q) {
            float s = acc[i][0][q] + acc[i][1][q] + acc[i][2][q] + acc[i][3][q];
            float ss = acc[i][0][q] * acc[i][0][q] + acc[i][1][q] * acc[i][1][q]
                     + acc[i][2][q] * acc[i][2][q] + acc[i][3][q] * acc[i][3][q];
            #pragma unroll
            for (int m = 1; m < 16; m <<= 1) { s += __shfl_xor(s, m); ss += __shfl_xor(ss, m); }
            if (lr == 0) { red[w][i * 16 + lg * 4 + q][0] = s; red[w][i * 16 + lg * 4 + q][1] = ss; }
        }
    __syncthreads();
    if (tid < 32) {
        float s = red[0][tid][0] + red[1][tid][0] + red[2][tid][0] + red[3][tid][0];
        float ss = red[0][tid][1] + red[1][tid][1] + red[2][tid][1] + red[3][tid][1];
        float mean = s * (1.f / 256.f);
        float var = ss * (1.f / 256.f) - mean * mean;
        mstd[tid] = make_float2(mean, rsqrtf(var + kEps));
    }
    __syncthreads();
    #pragma unroll
    for (int i = 0; i < 2; ++i)
        #pragma unroll
        for (int j = 0; j < 4; ++j) {
            int oc = w * 64 + j * 16 + lr;
            #pragma unroll
            for (int q = 0; q < 4; ++q) {
                int nn = i * 16 + lg * 4 + q;
                int node = n0 + nn;
                if (node < kN) {
                    float2 ms = mstd[nn];
                    float o = (acc[i][j][q] - ms.x) * ms.y * gv[j] + bvn[j];
                    x[(size_t)node * kH + oc] = o;
                    x_bf[(size_t)node * kH + oc] = f2bf(o);
                }
            }
        }
}

// ---------------- pooling (partial) + readout ------------------------------
__device__ __forceinline__ int lower_bound_i(const int* a, int n, int v) {
    int lo = 0, hi = n;
    while (lo < hi) { int m = (lo + hi) >> 1; if (a[m] < v) lo = m + 1; else hi = m; }
    return lo;
}

__global__ __launch_bounds__(256) void k_pool_part(
    const float* __restrict__ x, const int* __restrict__ batch,
    float* __restrict__ pooled)
{
    const int b = blockIdx.x >> 2, q = blockIdx.x & 3, t = threadIdx.x;
    const int s = lower_bound_i(batch, kN, b);
    const int e = lower_bound_i(batch, kN, b + 1);
    const int len = e - s;
    const int qs = s + (len * q) / 4;
    const int qe = s + (len * (q + 1)) / 4;
    float acc = 0.f;
    for (int i = qs; i < qe; ++i) acc += x[(size_t)i * kH + t];
    unsafeAtomicAdd(pooled + b * kH + t, acc);
}

__global__ __launch_bounds__(256) void k_ro(
    const float* __restrict__ pooled, const int* __restrict__ batch,
    const float* __restrict__ W1, const float* __restrict__ b1,
    const float* __restrict__ W2, const float* __restrict__ b2,
    float* __restrict__ out)
{
    __shared__ float ph[kH];
    __shared__ float h1[kH];
    const int b = blockIdx.x, t = threadIdx.x;
    const int s = lower_bound_i(batch, kN, b);
    const int e = lower_bound_i(batch, kN, b + 1);
    ph[t] = pooled[b * kH + t] / (float)(e - s);
    __syncthreads();
    float a = b1[t];
    for (int k = 0; k < kH; ++k) a = fmaf(ph[k], W1[k * kH + t], a);
    h1[t] = a > 0.f ? a : 0.f;
    __syncthreads();
    if (t < kC) {
        float o = b2[t];
        for (int k = 0; k < kH; ++k) o = fmaf(h1[k], W2[k * kC + t], o);
        out[b * kC + t] = o;
    }
}

// ---------------- launch ---------------------------------------------------
extern "C" void kernel_launch(void* const* d_in, const int* in_sizes, int n_in,
                              void* d_out, int out_size, void* d_ws, size_t ws_size,
                              hipStream_t stream)
{
    const float* nf     = (const float*)d_in[0];
    const void*  ei_raw = d_in[1];
    const float* ef     = (const float*)d_in[2];
    const void*  ba_raw = d_in[3];
    const float* node_W = (const float*)d_in[4];
    const float* node_b = (const float*)d_in[5];
    const float* edge_W = (const float*)d_in[6];
    const float* edge_b = (const float*)d_in[7];
    const float* msg_W1 = (const float*)d_in[8];
    const float* msg_b1 = (const float*)d_in[9];
    const float* msg_W2 = (const float*)d_in[10];
    const float* msg_b2 = (const float*)d_in[11];
    const float* upd_W1 = (const float*)d_in[12];
    const float* upd_b1 = (const float*)d_in[13];
    const float* upd_W2 = (const float*)d_in[14];
    const float* upd_b2 = (const float*)d_in[15];
    const float* ln_g   = (const float*)d_in[16];
    const float* ln_b   = (const float*)d_in[17];
    const float* ro_W1  = (const float*)d_in[18];
    const float* ro_b1  = (const float*)d_in[19];
    const float* ro_W2  = (const float*)d_in[20];
    const float* ro_b2  = (const float*)d_in[21];

    char* p = (char*)d_ws;
    auto alloc = [&](size_t bytes) { char* r = p; p += (bytes + 255) & ~(size_t)255; return r; };
    float* x    = (float*)alloc((size_t)kN * kH * 4);
    float* agg  = (float*)alloc((size_t)kN * kH * 4);
    float* pooled = (float*)alloc((size_t)kB * kH * 4);
    u16* x_bf   = (u16*)alloc((size_t)kN * kH * 2);
    u16* y_a    = (u16*)alloc((size_t)kN * kH * 2);
    u16* y_b    = (u16*)alloc((size_t)kN * kH * 2);
    u16* y_c    = (u16*)alloc((size_t)kN * kH * 2);
    u16* efs    = (u16*)alloc((size_t)kE * 64 * 2);
    u16* tm1 = (u16*)alloc((size_t)kL * 768 * 256 * 2);
    u16* tm2 = (u16*)alloc((size_t)kL * 256 * 256 * 2);
    u16* tu1 = (u16*)alloc((size_t)kL * 512 * 256 * 2);
    u16* tu2 = (u16*)alloc((size_t)kL * 256 * 256 * 2);
    u16* tmc = (u16*)alloc((size_t)kL * 64 * 256 * 2);
    float* b1p = (float*)alloc((size_t)kL * 256 * 4);
    int* ei32 = (int*)alloc((size_t)2 * kE * 4);
    int* ba32 = (int*)alloc((size_t)kN * 4);
    int* cnt  = (int*)alloc((size_t)kN * 4);
    int* cur  = (int*)alloc((size_t)kN * 4);
    int* rank = (int*)alloc((size_t)kE * 4);
    int* ssorted = (int*)alloc((size_t)kE * 4);
    int* dsorted = (int*)alloc((size_t)kE * 4);
    int* flag = (int*)alloc(4);

    k_detect_i64<<<1, 64, 0, stream>>>((const unsigned*)ei_raw, flag);
    k_cvt_idx<<<(2 * kE + 255) / 256, 256, 0, stream>>>((const unsigned*)ei_raw, flag, ei32, 2 * kE);
    k_cvt_idx<<<(kN + 255) / 256, 256, 0, stream>>>((const unsigned*)ba_raw, flag, ba32, kN);
    const int* src = ei32;
    const int* dst = ei32 + kE;

    hipMemsetAsync(cnt, 0, (size_t)kN * 4, stream);
    k_hist<<<(kE + 255) / 256, 256, 0, stream>>>(dst, cnt);
    k_scan<<<1, 256, 0, stream>>>(cnt, cur);
    k_scatter<<<(kE + 255) / 256, 256, 0, stream>>>(src, dst, cur, rank, ssorted, dsorted);

    const int prep_elems = kL * (768 + 256 + 512 + 256) * 256;
    k_prep_w<<<(prep_elems + 255) / 256, 256, 0, stream>>>(
        msg_W1, msg_W2, upd_W1, upd_W2, tm1, tm2, tu1, tu2);
    k_prep_m<<<dim3(kL, 4), 256, 0, stream>>>(edge_W, edge_b, msg_W1, msg_b1, tmc, b1p);
    k_prep_ef<<<(kE * 64 + 255) / 256, 256, 0, stream>>>(ef, rank, efs);

    k_encode_nodes<<<kN / 4, 256, 0, stream>>>(nf, node_W, node_b, x, x_bf);
    hipMemsetAsync(agg, 0, (size_t)kN * kH * sizeof(float), stream);
    hipMemsetAsync(pooled, 0, (size_t)kB * kH * sizeof(float), stream);

    for (int l = 0; l < kL; ++l) {
        k_node_pre<<<dim3((kN + 63) / 64, 3), 256, 0, stream>>>(
            x_bf, tm1 + (size_t)l * 768 * 256, tu1 + (size_t)l * 512 * 256,
            y_a, y_b, y_c);
        k_msg<<<kE / 128, 256, 0, stream>>>(efs, ssorted, dsorted, y_a, y_b,
            tmc + (size_t)l * 64 * 256, b1p + l * 256,
            tm2 + (size_t)l * 256 * 256, msg_b2 + l * kH, agg);
        k_upd<<<(kN + 31) / 32, 256, 0, stream>>>(x, x_bf, agg,
            tu1 + (size_t)l * 512 * 256 + 8 * 8192, upd_b1 + l * kH,
            tu2 + (size_t)l * 256 * 256, upd_b2 + l * kH,
            ln_g + l * kH, ln_b + l * kH, y_c);
    }

    k_pool_part<<<kB * 4, 256, 0, stream>>>(x, ba32, pooled);
    k_ro<<<kB, 256, 0, stream>>>(pooled, ba32, ro_W1, ro_b1, ro_W2, ro_b2, (float*)d_out);
}

// Round 15
// 544.453 us; speedup vs baseline: 1.9962x; 1.9962x over previous
//
#include <hip/hip_runtime.h>
#include <cstdint>
#include <cstddef>

// ---------------------------------------------------------------------------
// GraphMathSolver: 4-layer MPNN on MI355X.
// Round 15: REVERT to round-13 best (544.6us).
//   Round 14's two-tile k_msg spilled (ya1/yb1 live across scan -> scratch,
//   FETCH 36->174MB, WRITE 12->268MB, 200us). k_msg is at its gather-latency
//   floor at this tile shape; this restores the proven configuration.
// ---------------------------------------------------------------------------

typedef unsigned short u16;
typedef __attribute__((ext_vector_type(4))) float f32x4;
typedef __attribute__((ext_vector_type(8))) short bf16x8;
typedef __attribute__((ext_vector_type(4))) short s16x4;

constexpr int kN  = 10000;
constexpr int kE  = 160000;
constexpr int kB  = 64;
constexpr int kH  = 256;
constexpr int kL  = 4;
constexpr int kC  = 10;
constexpr float kEps = 1e-5f;

struct __align__(16) F4 { float v[4]; };
__device__ __forceinline__ F4 ldF4(const float* p) { return *reinterpret_cast<const F4*>(p); }

__device__ __forceinline__ u16 f2bf(float f) {
    unsigned u = __builtin_bit_cast(unsigned, f);
    return (u16)((u + 0x7fffu + ((u >> 16) & 1u)) >> 16);
}
__device__ __forceinline__ float bf2f(u16 h) {
    return __builtin_bit_cast(float, (unsigned)h << 16);
}
__device__ __forceinline__ unsigned cvtpk(float lo, float hi) {
    unsigned r;
    asm("v_cvt_pk_bf16_f32 %0, %1, %2" : "=v"(r) : "v"(lo), "v"(hi));
    return r;
}

// ---- async global->LDS DMA, 16B per lane ----------------------------------
typedef __attribute__((address_space(1))) void GV;
typedef __attribute__((address_space(3))) void LV;
__device__ __forceinline__ void gl_lds16(const void* g, void* l) {
    __builtin_amdgcn_global_load_lds((GV*)g, (LV*)l, 16, 0, 0);
}
__device__ __forceinline__ void dma_w16k(const u16* __restrict__ Wc, char* lds, int tid) {
    const int w = tid >> 6, lane = tid & 63;
    char* lb = lds + w * 4096;
    const char* gb = (const char*)Wc + w * 4096 + lane * 16;
    #pragma unroll
    for (int i = 0; i < 4; ++i) gl_lds16(gb + i * 1024, lb + i * 1024);
}

// direct global fragment read from swizzled-linear chunk layout [n=256][k=32]
__device__ __forceinline__ bf16x8 g_frag(const u16* __restrict__ g, int n, int kg) {
    return *reinterpret_cast<const bf16x8*>(g + n * 32 + ((kg ^ ((n >> 1) & 3)) << 3));
}
// LDS fragment readers (XOR-swizzled)
__device__ __forceinline__ bf16x8 rdfrag(const char* lds, int n, int kg) {
    return *reinterpret_cast<const bf16x8*>(lds + n * 64 + ((kg ^ ((n >> 1) & 3)) << 4));
}
__device__ __forceinline__ bf16x8 rdH(const char* H, int row, int kbyte) {
    return *reinterpret_cast<const bf16x8*>(H + row * 512 + (kbyte ^ ((row & 7) << 4)));
}

// ---------------- int64/int32 index handling -------------------------------
__global__ void k_detect_i64(const unsigned* __restrict__ w, int* __restrict__ flag) {
    if (threadIdx.x == 0 && blockIdx.x == 0) {
        int is64 = 1;
        for (int i = 0; i < 64; ++i)
            if (w[2*i + 1] != 0u) { is64 = 0; break; }
        *flag = is64;
    }
}
__global__ void k_cvt_idx(const unsigned* __restrict__ w, const int* __restrict__ flag,
                          int* __restrict__ out, int n) {
    int i = blockIdx.x * 256 + threadIdx.x;
    if (i < n) out[i] = (*flag) ? (int)w[2*i] : (int)w[i];
}

// ---------------- counting sort of edges by dst ----------------------------
__global__ __launch_bounds__(256) void k_hist(const int* __restrict__ dst,
                                              int* __restrict__ cnt) {
    int e = blockIdx.x * 256 + threadIdx.x;
    if (e < kE) atomicAdd(&cnt[dst[e]], 1);
}
__global__ __launch_bounds__(256) void k_scan(const int* __restrict__ cnt,
                                              int* __restrict__ cur) {
    __shared__ int part[256];
    const int t = threadIdx.x;
    const int per = (kN + 255) / 256;
    int s = 0;
    for (int i = 0; i < per; ++i) {
        int idx = t * per + i;
        if (idx < kN) s += cnt[idx];
    }
    int own = s;
    part[t] = s; __syncthreads();
    for (int off = 1; off < 256; off <<= 1) {
        int v = (t >= off) ? part[t - off] : 0;
        __syncthreads();
        part[t] += v;
        __syncthreads();
    }
    int run = part[t] - own;
    for (int i = 0; i < per; ++i) {
        int idx = t * per + i;
        if (idx < kN) { cur[idx] = run; run += cnt[idx]; }
    }
}
__global__ __launch_bounds__(256) void k_scatter(
    const int* __restrict__ src, const int* __restrict__ dst,
    int* __restrict__ cur, int* __restrict__ rank,
    int* __restrict__ ssorted, int* __restrict__ dsorted) {
    int e = blockIdx.x * 256 + threadIdx.x;
    if (e < kE) {
        int d = dst[e];
        int p = atomicAdd(&cur[d], 1);
        rank[e] = p;
        ssorted[p] = src[e];
        dsorted[p] = d;
    }
}

// ---- weight prep: fp32 [L][K][256] -> bf16 swizzled-linear [L][kc][n][32] --
__global__ __launch_bounds__(256) void k_prep_w(
    const float* __restrict__ mW1, const float* __restrict__ mW2,
    const float* __restrict__ uW1, const float* __restrict__ uW2,
    u16* __restrict__ tm1, u16* __restrict__ tm2,
    u16* __restrict__ tu1, u16* __restrict__ tu2)
{
    int idx = blockIdx.x * 256 + threadIdx.x;
    const int S1 = kL * 768 * 256;
    const int S2 = S1 + kL * 256 * 256;
    const int S3 = S2 + kL * 512 * 256;
    const int S4 = S3 + kL * 256 * 256;
    const float* src; u16* dst; int K, r;
    if (idx < S1)      { src = mW1; dst = tm1; K = 768; r = idx; }
    else if (idx < S2) { src = mW2; dst = tm2; K = 256; r = idx - S1; }
    else if (idx < S3) { src = uW1; dst = tu1; K = 512; r = idx - S2; }
    else if (idx < S4) { src = uW2; dst = tu2; K = 256; r = idx - S3; }
    else return;
    int per = K * 256;
    int layer = r / per, rr = r - layer * per;
    int k = rr >> 8, n = rr & 255;
    int kc = k >> 5, kg = (k >> 3) & 3, e = k & 7;
    dst[(size_t)layer * per + (size_t)kc * 8192 + n * 32 + ((kg ^ ((n >> 1) & 3)) << 3) + e]
        = f2bf(src[(size_t)layer * per + rr]);
}

// ---- ef prep: LINEAR read, rank-scattered write into block chunk layout ----
__global__ __launch_bounds__(256) void k_prep_ef(
    const float* __restrict__ ef, const int* __restrict__ rank,
    u16* __restrict__ efs)
{
    int idx = blockIdx.x * 256 + threadIdx.x;
    if (idx >= kE * 64) return;
    int e = idx >> 6, k = idx & 63;
    float v = ef[idx];                      // coalesced linear read
    int p = rank[e];
    int row = p & 63, blk = p >> 6;
    int kc = k >> 5, kg = (k >> 3) & 3, ee = k & 7;
    efs[(size_t)blk * 4096 + kc * 2048 + row * 32
        + ((kg ^ ((row >> 1) & 3)) << 3) + ee] = f2bf(v);
}

// ---- M[l] = We @ W1c[l] (64x256), b1'[l] = b1[l] + be @ W1c[l] -------------
__global__ __launch_bounds__(256) void k_prep_m(
    const float* __restrict__ eW, const float* __restrict__ eb,
    const float* __restrict__ mW1, const float* __restrict__ mb1,
    u16* __restrict__ tmc, float* __restrict__ b1p)
{
    __shared__ float sWe[16 * 256];
    const int l = blockIdx.x, rq = blockIdx.y, t = threadIdx.x;
    const int r0 = rq * 16;
    #pragma unroll
    for (int i = 0; i < 16; ++i) sWe[i * 256 + t] = eW[(size_t)(r0 + i) * 256 + t];
    __syncthreads();
    const float* W1c = mW1 + (size_t)l * 768 * 256 + (size_t)512 * 256;
    float m[16];
    #pragma unroll
    for (int r = 0; r < 16; ++r) m[r] = 0.f;
    float bp = (rq == 0) ? mb1[l * 256 + t] : 0.f;
    for (int j = 0; j < 256; ++j) {
        float wv = W1c[(size_t)j * 256 + t];
        if (rq == 0) bp = fmaf(eb[j], wv, bp);
        #pragma unroll
        for (int r = 0; r < 16; ++r) m[r] = fmaf(sWe[r * 256 + j], wv, m[r]);
    }
    if (rq == 0) b1p[l * 256 + t] = bp;
    #pragma unroll
    for (int r = 0; r < 16; ++r) {
        int k = r0 + r;
        int kc = k >> 5, kg = (k >> 3) & 3, e = k & 7;
        tmc[(size_t)l * 16384 + (size_t)kc * 8192 + t * 32
            + ((kg ^ ((t >> 1) & 3)) << 3) + e] = f2bf(m[r]);
    }
}

// ---------------- node encoder (scalar fp32, small) ------------------------
__global__ __launch_bounds__(256) void k_encode_nodes(
    const float* __restrict__ nf, const float* __restrict__ W,
    const float* __restrict__ b, float* __restrict__ x, u16* __restrict__ x_bf)
{
    __shared__ float s_nf[4 * 128];
    const int n0 = blockIdx.x * 4;
    const int tid = threadIdx.x;
    reinterpret_cast<float2*>(s_nf)[tid] =
        reinterpret_cast<const float2*>(nf + (size_t)n0 * 128)[tid];
    __syncthreads();
    float acc[4] = {0.f, 0.f, 0.f, 0.f};
    for (int k = 0; k < 128; ++k) {
        float w = W[k * kH + tid];
        #pragma unroll
        for (int r = 0; r < 4; ++r) acc[r] = fmaf(s_nf[r * 128 + k], w, acc[r]);
    }
    float bias = b[tid];
    #pragma unroll
    for (int r = 0; r < 4; ++r) {
        float o = acc[r] + bias;
        x[(size_t)(n0 + r) * kH + tid] = o;
        x_bf[(size_t)(n0 + r) * kH + tid] = f2bf(o);
    }
}

// ---------------- per-node pre-GEMM: y_{a,b,c}, dbuf single-barrier --------
__global__ __launch_bounds__(256, 3) void k_node_pre(
    const u16* __restrict__ x_bf, const u16* __restrict__ Wtm1,
    const u16* __restrict__ Wtu1,
    u16* __restrict__ y_a, u16* __restrict__ y_b, u16* __restrict__ y_c)
{
    __shared__ char sWt[2][16384];
    __shared__ char sA[2][4096];
    const int tid = threadIdx.x;
    const int n0 = blockIdx.x * 64;
    const int half = blockIdx.y;
    const u16* Wt = (half == 2) ? Wtu1 : Wtm1 + (size_t)half * 8 * 8192;
    u16* y = (half == 0) ? y_a : (half == 1 ? y_b : y_c);
    const int w = tid >> 6, lane = tid & 63;
    const int lr = lane & 15, lg = lane >> 4;
    const int srow = tid >> 2, skg = tid & 3;
    const int kg_src = skg ^ ((srow >> 1) & 3);
    int gnode = n0 + srow; if (gnode >= kN) gnode = kN - 1;

    f32x4 acc[4][4];
    #pragma unroll
    for (int i = 0; i < 4; ++i)
        #pragma unroll
        for (int j = 0; j < 4; ++j) acc[i][j] = (f32x4){0.f, 0.f, 0.f, 0.f};

    dma_w16k(Wt, sWt[0], tid);
    gl_lds16(x_bf + (size_t)gnode * kH + kg_src * 8, sA[0] + w * 1024);
    __syncthreads();

    for (int kc = 0; kc < 8; ++kc) {
        const int cur = kc & 1, nxt = cur ^ 1;
        if (kc < 7) {
            dma_w16k(Wt + (size_t)(kc + 1) * 8192, sWt[nxt], tid);
            gl_lds16(x_bf + (size_t)gnode * kH + (kc + 1) * 32 + kg_src * 8,
                     sA[nxt] + w * 1024);
        }
        bf16x8 af[4], bfm[4];
        #pragma unroll
        for (int i = 0; i < 4; ++i) af[i] = rdfrag(sWt[cur], w * 64 + i * 16 + lr, lg);
        #pragma unroll
        for (int j = 0; j < 4; ++j) bfm[j] = rdfrag(sA[cur], j * 16 + lr, lg);
        #pragma unroll
        for (int i = 0; i < 4; ++i)
            #pragma unroll
            for (int j = 0; j < 4; ++j)
                acc[i][j] = __builtin_amdgcn_mfma_f32_16x16x32_bf16(af[i], bfm[j], acc[i][j], 0, 0, 0);
        __syncthreads();
    }
    #pragma unroll
    for (int i = 0; i < 4; ++i) {
        const int hc0 = w * 64 + i * 16 + lg * 4;
        #pragma unroll
        for (int j = 0; j < 4; ++j) {
            const int node = n0 + j * 16 + lr;
            if (node < kN) {
                uint2 o;
                o.x = cvtpk(acc[i][j][0], acc[i][j][1]);
                o.y = cvtpk(acc[i][j][2], acc[i][j][3]);
                *reinterpret_cast<uint2*>(y + (size_t)node * kH + hc0) = o;
            }
        }
    }
}

// ---------------- edge message MLP + segmented scatter ---------------------
// h1 = relu(y_a[src]+y_b[dst]+ef@M+b1'); msg = h1@W2.
// 32KB LDS; lb(256,4) so no VGPR spill; HW co-schedules 5th block via LDS.
__global__ __launch_bounds__(256, 4) void k_msg(
    const u16* __restrict__ efs,
    const int* __restrict__ ssorted, const int* __restrict__ dsorted,
    const u16* __restrict__ y_a, const u16* __restrict__ y_b,
    const u16* __restrict__ Wtm, const float* __restrict__ b1p,
    const u16* __restrict__ Wt2, const float* __restrict__ b2,
    float* __restrict__ agg)
{
    __shared__ __align__(16) char sBuf[32768]; // h1 -> msg [64][256] bf16 swz

    const int tid = threadIdx.x;
    const int nwg = gridDim.x;
    const int q8 = nwg >> 3, r8 = nwg & 7;
    const int xcd = blockIdx.x & 7, sub = blockIdx.x >> 3;
    const int bid = (xcd < r8 ? xcd * (q8 + 1) : r8 * (q8 + 1) + (xcd - r8) * q8) + sub;
    const int e0 = bid * 64;

    const int w = tid >> 6, lane = tid & 63;
    const int lr = lane & 15, lg = lane >> 4;

    // per-wave dst regs + boundary mask (no LDS)
    const int myDst = dsorted[e0 + lane];
    const int nxtDst = __shfl_down(myDst, 1);
    const unsigned long long bmask = __ballot(lane == 63 || myDst != nxtDst);
    const unsigned mlo = __builtin_amdgcn_readfirstlane((unsigned)(bmask & 0xffffffffu));
    const unsigned mhi = __builtin_amdgcn_readfirstlane((unsigned)(bmask >> 32));

    // ---- y gathers issued early ----
    uint2 ya[4][4], yb[4][4];
    #pragma unroll
    for (int j = 0; j < 4; ++j) {
        const int es = ssorted[e0 + j * 16 + lr];
        const int ed = __shfl(myDst, j * 16 + lr);
        const u16* pa = y_a + (size_t)es * kH;
        const u16* pb = y_b + (size_t)ed * kH;
        #pragma unroll
        for (int i = 0; i < 4; ++i) {
            const int hc0 = w * 64 + i * 16 + lg * 4;
            ya[j][i] = *reinterpret_cast<const uint2*>(pa + hc0);
            yb[j][i] = *reinterpret_cast<const uint2*>(pb + hc0);
        }
    }

    f32x4 acc[4][4];
    #pragma unroll
    for (int i = 0; i < 4; ++i)
        #pragma unroll
        for (int j = 0; j < 4; ++j) acc[i][j] = (f32x4){0.f, 0.f, 0.f, 0.f};

    // ---- GEMM1 (swapped): pe^T = M^T @ ef^T, K = 64, no barriers ----
    #pragma unroll
    for (int kc = 0; kc < 2; ++kc) {
        const u16* efc = efs + (size_t)bid * 4096 + kc * 2048;
        bf16x8 af[4], bfm[4];
        #pragma unroll
        for (int i = 0; i < 4; ++i) af[i] = g_frag(Wtm + kc * 8192, w * 64 + i * 16 + lr, lg);
        #pragma unroll
        for (int j = 0; j < 4; ++j) {
            int row = j * 16 + lr;
            bfm[j] = *reinterpret_cast<const bf16x8*>(
                efc + row * 32 + ((lg ^ ((row >> 1) & 3)) << 3));
        }
        #pragma unroll
        for (int i = 0; i < 4; ++i)
            #pragma unroll
            for (int j = 0; j < 4; ++j)
                acc[i][j] = __builtin_amdgcn_mfma_f32_16x16x32_bf16(af[i], bfm[j], acc[i][j], 0, 0, 0);
    }

    // ---- epilogue 1: h1 = relu(pe + b1' + y_a[src] + y_b[dst]) -> sBuf ----
    #pragma unroll
    for (int j = 0; j < 4; ++j) {
        const int edge = j * 16 + lr;
        #pragma unroll
        for (int i = 0; i < 4; ++i) {
            const int hc0 = w * 64 + i * 16 + lg * 4;
            const F4 bb = ldF4(b1p + hc0);
            float s0 = __builtin_bit_cast(float, ya[j][i].x << 16) + __builtin_bit_cast(float, yb[j][i].x << 16);
            float s1 = __builtin_bit_cast(float, ya[j][i].x & 0xffff0000u) + __builtin_bit_cast(float, yb[j][i].x & 0xffff0000u);
            float s2 = __builtin_bit_cast(float, ya[j][i].y << 16) + __builtin_bit_cast(float, yb[j][i].y << 16);
            float s3 = __builtin_bit_cast(float, ya[j][i].y & 0xffff0000u) + __builtin_bit_cast(float, yb[j][i].y & 0xffff0000u);
            float h0 = acc[i][j][0] + bb.v[0] + s0; h0 = h0 > 0.f ? h0 : 0.f;
            float h1 = acc[i][j][1] + bb.v[1] + s1; h1 = h1 > 0.f ? h1 : 0.f;
            float h2 = acc[i][j][2] + bb.v[2] + s2; h2 = h2 > 0.f ? h2 : 0.f;
            float h3 = acc[i][j][3] + bb.v[3] + s3; h3 = h3 > 0.f ? h3 : 0.f;
            uint2 o; o.x = cvtpk(h0, h1); o.y = cvtpk(h2, h3);
            int byte = edge * 512 + hc0 * 2;
            *reinterpret_cast<uint2*>(sBuf + (byte ^ ((edge & 7) << 4))) = o;
            acc[i][j] = (f32x4){0.f, 0.f, 0.f, 0.f};
        }
    }
    __syncthreads();

    // ---- GEMM2 (normal): msg = h1 @ W2, K = 256, no stage barriers ----
    #pragma unroll 2
    for (int kc = 0; kc < 8; ++kc) {
        bf16x8 af2[4], bf2[4];
        #pragma unroll
        for (int i = 0; i < 4; ++i) af2[i] = rdH(sBuf, i * 16 + lr, kc * 64 + lg * 16);
        #pragma unroll
        for (int j = 0; j < 4; ++j) bf2[j] = g_frag(Wt2 + kc * 8192, w * 64 + j * 16 + lr, lg);
        #pragma unroll
        for (int i = 0; i < 4; ++i)
            #pragma unroll
            for (int j = 0; j < 4; ++j)
                acc[i][j] = __builtin_amdgcn_mfma_f32_16x16x32_bf16(af2[i], bf2[j], acc[i][j], 0, 0, 0);
    }
    __syncthreads();

    // ---- dump msg (bf16) into sBuf (in-place swizzled) ----
    #pragma unroll
    for (int j = 0; j < 4; ++j) {
        const int oc = w * 64 + j * 16 + lr;
        const float b2v = b2[oc];
        #pragma unroll
        for (int i = 0; i < 4; ++i) {
            unsigned p01 = cvtpk(acc[i][j][0] + b2v, acc[i][j][1] + b2v);
            unsigned p23 = cvtpk(acc[i][j][2] + b2v, acc[i][j][3] + b2v);
            int eb0 = i * 16 + lg * 4;
            *reinterpret_cast<u16*>(sBuf + (((eb0 + 0) * 512 + oc * 2) ^ (((eb0 + 0) & 7) << 4))) = (u16)p01;
            *reinterpret_cast<u16*>(sBuf + (((eb0 + 1) * 512 + oc * 2) ^ (((eb0 + 1) & 7) << 4))) = (u16)(p01 >> 16);
            *reinterpret_cast<u16*>(sBuf + (((eb0 + 2) * 512 + oc * 2) ^ (((eb0 + 2) & 7) << 4))) = (u16)p23;
            *reinterpret_cast<u16*>(sBuf + (((eb0 + 3) * 512 + oc * 2) ^ (((eb0 + 3) & 7) << 4))) = (u16)(p23 >> 16);
        }
    }
    __syncthreads();

    // ---- per-col segmented scan; wave-uniform flush via SGPR mask ----
    {
        const int col = tid;
        float run = 0.f;
        #pragma unroll
        for (int e = 0; e < 64; ++e) {
            int byte = e * 512 + col * 2;
            run += bf2f(*reinterpret_cast<const u16*>(sBuf + (byte ^ ((e & 7) << 4))));
            unsigned mm = (e < 32) ? mlo : mhi;
            if ((mm >> (e & 31)) & 1u) {
                int d = __shfl(myDst, e);
                unsafeAtomicAdd(agg + (size_t)d * kH + col, run);
                run = 0.f;
            }
        }
    }
}

// ---------------- node update: 32-row tiles, agg-only GEMM1 + y_c ----------
__global__ __launch_bounds__(256, 3) void k_upd(
    float* __restrict__ x, u16* __restrict__ x_bf,
    float* __restrict__ agg,
    const u16* __restrict__ Wt1b, const float* __restrict__ b1,
    const u16* __restrict__ Wt2, const float* __restrict__ b2,
    const float* __restrict__ lng, const float* __restrict__ lnb,
    const u16* __restrict__ y_c)
{
    __shared__ char sWt[2][16384];
    __shared__ char sA[2][2048];   // agg tile [32 rows][32 k] bf16 swz
    __shared__ char sH[16384];     // h tile [32 rows][256] bf16 swz

    const int tid = threadIdx.x;
    const int n0 = blockIdx.x * 32;
    const int w = tid >> 6, lane = tid & 63;
    const int lr = lane & 15, lg = lane >> 4;
    const int srow = tid >> 2, skg = tid & 3;
    int gnode = n0 + (srow & 31); if (gnode >= kN) gnode = kN - 1;
    const bool stg = tid < 128;

    // hoisted y_c gathers (hide latency under GEMM1)
    uint2 ycv[4][2];
    #pragma unroll
    for (int i = 0; i < 4; ++i) {
        const int hc0 = w * 64 + i * 16 + lg * 4;
        #pragma unroll
        for (int j = 0; j < 2; ++j) {
            int ncl = n0 + j * 16 + lr; if (ncl >= kN) ncl = kN - 1;
            ycv[i][j] = *reinterpret_cast<const uint2*>(y_c + (size_t)ncl * kH + hc0);
        }
    }

    f32x4 acc[4][4];
    #pragma unroll
    for (int i = 0; i < 4; ++i)
        #pragma unroll
        for (int j = 0; j < 4; ++j) acc[i][j] = (f32x4){0.f, 0.f, 0.f, 0.f};

    dma_w16k(Wt1b, sWt[0], tid);
    if (stg) {
        const float* ap = agg + (size_t)gnode * kH + skg * 8;
        F4 a0 = ldF4(ap), a1 = ldF4(ap + 4);
        int4 bv;
        bv.x = (int)cvtpk(a0.v[0], a0.v[1]);
        bv.y = (int)cvtpk(a0.v[2], a0.v[3]);
        bv.z = (int)cvtpk(a1.v[0], a1.v[1]);
        bv.w = (int)cvtpk(a1.v[2], a1.v[3]);
        *reinterpret_cast<int4*>(sA[0] + srow * 64 + ((skg ^ ((srow >> 1) & 3)) << 4)) = bv;
    }
    __syncthreads();

    // ---- GEMM1 (swapped): h^T = uW1b^T @ agg^T, K = 256 = 8 chunks ----
    for (int kc = 0; kc < 8; ++kc) {
        const int cur = kc & 1, nxt = cur ^ 1;
        bool pf = false; F4 a0, a1;
        if (kc < 7) {
            dma_w16k(Wt1b + (size_t)(kc + 1) * 8192, sWt[nxt], tid);
            if (stg) {
                const float* ap = agg + (size_t)gnode * kH + (kc + 1) * 32 + skg * 8;
                a0 = ldF4(ap); a1 = ldF4(ap + 4); pf = true;
            }
        } else {
            dma_w16k(Wt2, sWt[nxt], tid);
        }
        bf16x8 af[4], bfm[2];
        #pragma unroll
        for (int i = 0; i < 4; ++i) af[i] = rdfrag(sWt[cur], w * 64 + i * 16 + lr, lg);
        #pragma unroll
        for (int j = 0; j < 2; ++j) bfm[j] = rdfrag(sA[cur], j * 16 + lr, lg);
        #pragma unroll
        for (int i = 0; i < 4; ++i)
            #pragma unroll
            for (int j = 0; j < 2; ++j)
                acc[i][j] = __builtin_amdgcn_mfma_f32_16x16x32_bf16(af[i], bfm[j], acc[i][j], 0, 0, 0);
        if (pf) {
            int4 bv;
            bv.x = (int)cvtpk(a0.v[0], a0.v[1]);
            bv.y = (int)cvtpk(a0.v[2], a0.v[3]);
            bv.z = (int)cvtpk(a1.v[0], a1.v[1]);
            bv.w = (int)cvtpk(a1.v[2], a1.v[3]);
            *reinterpret_cast<int4*>(sA[nxt] + srow * 64 + ((skg ^ ((srow >> 1) & 3)) << 4)) = bv;
        }
        __syncthreads();
    }

    // ---- epilogue 1: h = relu(acc + b1 + y_c[node]) -> sH ----
    #pragma unroll
    for (int i = 0; i < 4; ++i) {
        const int hc0 = w * 64 + i * 16 + lg * 4;
        const F4 bb = ldF4(b1 + hc0);
        #pragma unroll
        for (int j = 0; j < 2; ++j) {
            const int row = j * 16 + lr;
            float s0 = __builtin_bit_cast(float, ycv[i][j].x << 16);
            float s1 = __builtin_bit_cast(float, ycv[i][j].x & 0xffff0000u);
            float s2 = __builtin_bit_cast(float, ycv[i][j].y << 16);
            float s3 = __builtin_bit_cast(float, ycv[i][j].y & 0xffff0000u);
            float h0 = acc[i][j][0] + bb.v[0] + s0; h0 = h0 > 0.f ? h0 : 0.f;
            float h1 = acc[i][j][1] + bb.v[1] + s1; h1 = h1 > 0.f ? h1 : 0.f;
            float h2 = acc[i][j][2] + bb.v[2] + s2; h2 = h2 > 0.f ? h2 : 0.f;
            float h3 = acc[i][j][3] + bb.v[3] + s3; h3 = h3 > 0.f ? h3 : 0.f;
            uint2 o; o.x = cvtpk(h0, h1); o.y = cvtpk(h2, h3);
            int byte = row * 512 + hc0 * 2;
            *reinterpret_cast<uint2*>(sH + (byte ^ ((row & 7) << 4))) = o;
            acc[i][j] = (f32x4){0.f, 0.f, 0.f, 0.f};
        }
    }
    __syncthreads();

    // zero this block's agg rows for the next layer (all reads done)
    {
        float4 z = make_float4(0.f, 0.f, 0.f, 0.f);
        float4* bp = reinterpret_cast<float4*>(agg + (size_t)n0 * kH);
        #pragma unroll
        for (int i = 0; i < 8; ++i) {
            int idx = i * 256 + tid;
            int row = idx >> 6;
            if (n0 + row < kN) bp[idx] = z;
        }
    }

    // ---- GEMM2 (normal): upd = h @ uW2, K = 256 = 8 chunks ----
    for (int kc = 0; kc < 8; ++kc) {
        const int cur = kc & 1, nxt = cur ^ 1;
        if (kc < 7) dma_w16k(Wt2 + (size_t)(kc + 1) * 8192, sWt[nxt], tid);
        bf16x8 af2[2], bf2[4];
        #pragma unroll
        for (int i = 0; i < 2; ++i) af2[i] = rdH(sH, i * 16 + lr, kc * 64 + lg * 16);
        #pragma unroll
        for (int j = 0; j < 4; ++j) bf2[j] = rdfrag(sWt[cur], w * 64 + j * 16 + lr, lg);
        #pragma unroll
        for (int i = 0; i < 2; ++i)
            #pragma unroll
            for (int j = 0; j < 4; ++j)
                acc[i][j] = __builtin_amdgcn_mfma_f32_16x16x32_bf16(af2[i], bf2[j], acc[i][j], 0, 0, 0);
        __syncthreads();
    }

    // ---- epilogue 2: + b2 + x (residual), LayerNorm over 32 nodes ----
    float b2v[4], gv[4], bvn[4];
    #pragma unroll
    for (int j = 0; j < 4; ++j) {
        int oc = w * 64 + j * 16 + lr;
        b2v[j] = b2[oc]; gv[j] = lng[oc]; bvn[j] = lnb[oc];
    }
    #pragma unroll
    for (int i = 0; i < 2; ++i)
        #pragma unroll
        for (int j = 0; j < 4; ++j) {
            int oc = w * 64 + j * 16 + lr;
            #pragma unroll
            for (int q = 0; q < 4; ++q) {
                int node = n0 + i * 16 + lg * 4 + q;
                int ncl = node < kN ? node : kN - 1;
                acc[i][j][q] += b2v[j] + x[(size_t)ncl * kH + oc];
            }
        }

    float (*red)[32][2] = reinterpret_cast<float(*)[32][2]>(sA[0]);
    float2* mstd = reinterpret_cast<float2*>((char*)sA[0] + 1024);
    #pragma unroll
    for (int i = 0; i < 2; ++i)
        #pragma unroll
        for (int q = 0; q < 4; ++q) {
            float s = acc[i][0][q] + acc[i][1][q] + acc[i][2][q] + acc[i][3][q];
            float ss = acc[i][0][q] * acc[i][0][q] + acc[i][1][q] * acc[i][1][q]
                     + acc[i][2][q] * acc[i][2][q] + acc[i][3][q] * acc[i][3][q];
            #pragma unroll
            for (int m = 1; m < 16; m <<= 1) { s += __shfl_xor(s, m); ss += __shfl_xor(ss, m); }
            if (lr == 0) { red[w][i * 16 + lg * 4 + q][0] = s; red[w][i * 16 + lg * 4 + q][1] = ss; }
        }
    __syncthreads();
    if (tid < 32) {
        float s = red[0][tid][0] + red[1][tid][0] + red[2][tid][0] + red[3][tid][0];
        float ss = red[0][tid][1] + red[1][tid][1] + red[2][tid][1] + red[3][tid][1];
        float mean = s * (1.f / 256.f);
        float var = ss * (1.f / 256.f) - mean * mean;
        mstd[tid] = make_float2(mean, rsqrtf(var + kEps));
    }
    __syncthreads();
    #pragma unroll
    for (int i = 0; i < 2; ++i)
        #pragma unroll
        for (int j = 0; j < 4; ++j) {
            int oc = w * 64 + j * 16 + lr;
            #pragma unroll
            for (int q = 0; q < 4; ++q) {
                int nn = i * 16 + lg * 4 + q;
                int node = n0 + nn;
                if (node < kN) {
                    float2 ms = mstd[nn];
                    float o = (acc[i][j][q] - ms.x) * ms.y * gv[j] + bvn[j];
                    x[(size_t)node * kH + oc] = o;
                    x_bf[(size_t)node * kH + oc] = f2bf(o);
                }
            }
        }
}

// ---------------- pooling (partial) + readout ------------------------------
__device__ __forceinline__ int lower_bound_i(const int* a, int n, int v) {
    int lo = 0, hi = n;
    while (lo < hi) { int m = (lo + hi) >> 1; if (a[m] < v) lo = m + 1; else hi = m; }
    return lo;
}

__global__ __launch_bounds__(256) void k_pool_part(
    const float* __restrict__ x, const int* __restrict__ batch,
    float* __restrict__ pooled)
{
    const int b = blockIdx.x >> 2, q = blockIdx.x & 3, t = threadIdx.x;
    const int s = lower_bound_i(batch, kN, b);
    const int e = lower_bound_i(batch, kN, b + 1);
    const int len = e - s;
    const int qs = s + (len * q) / 4;
    const int qe = s + (len * (q + 1)) / 4;
    float acc = 0.f;
    for (int i = qs; i < qe; ++i) acc += x[(size_t)i * kH + t];
    unsafeAtomicAdd(pooled + b * kH + t, acc);
}

__global__ __launch_bounds__(256) void k_ro(
    const float* __restrict__ pooled, const int* __restrict__ batch,
    const float* __restrict__ W1, const float* __restrict__ b1,
    const float* __restrict__ W2, const float* __restrict__ b2,
    float* __restrict__ out)
{
    __shared__ float ph[kH];
    __shared__ float h1[kH];
    const int b = blockIdx.x, t = threadIdx.x;
    const int s = lower_bound_i(batch, kN, b);
    const int e = lower_bound_i(batch, kN, b + 1);
    ph[t] = pooled[b * kH + t] / (float)(e - s);
    __syncthreads();
    float a = b1[t];
    for (int k = 0; k < kH; ++k) a = fmaf(ph[k], W1[k * kH + t], a);
    h1[t] = a > 0.f ? a : 0.f;
    __syncthreads();
    if (t < kC) {
        float o = b2[t];
        for (int k = 0; k < kH; ++k) o = fmaf(h1[k], W2[k * kC + t], o);
        out[b * kC + t] = o;
    }
}

// ---------------- launch ---------------------------------------------------
extern "C" void kernel_launch(void* const* d_in, const int* in_sizes, int n_in,
                              void* d_out, int out_size, void* d_ws, size_t ws_size,
                              hipStream_t stream)
{
    const float* nf     = (const float*)d_in[0];
    const void*  ei_raw = d_in[1];
    const float* ef     = (const float*)d_in[2];
    const void*  ba_raw = d_in[3];
    const float* node_W = (const float*)d_in[4];
    const float* node_b = (const float*)d_in[5];
    const float* edge_W = (const float*)d_in[6];
    const float* edge_b = (const float*)d_in[7];
    const float* msg_W1 = (const float*)d_in[8];
    const float* msg_b1 = (const float*)d_in[9];
    const float* msg_W2 = (const float*)d_in[10];
    const float* msg_b2 = (const float*)d_in[11];
    const float* upd_W1 = (const float*)d_in[12];
    const float* upd_b1 = (const float*)d_in[13];
    const float* upd_W2 = (const float*)d_in[14];
    const float* upd_b2 = (const float*)d_in[15];
    const float* ln_g   = (const float*)d_in[16];
    const float* ln_b   = (const float*)d_in[17];
    const float* ro_W1  = (const float*)d_in[18];
    const float* ro_b1  = (const float*)d_in[19];
    const float* ro_W2  = (const float*)d_in[20];
    const float* ro_b2  = (const float*)d_in[21];

    char* p = (char*)d_ws;
    auto alloc = [&](size_t bytes) { char* r = p; p += (bytes + 255) & ~(size_t)255; return r; };
    float* x    = (float*)alloc((size_t)kN * kH * 4);
    float* agg  = (float*)alloc((size_t)kN * kH * 4);
    float* pooled = (float*)alloc((size_t)kB * kH * 4);
    u16* x_bf   = (u16*)alloc((size_t)kN * kH * 2);
    u16* y_a    = (u16*)alloc((size_t)kN * kH * 2);
    u16* y_b    = (u16*)alloc((size_t)kN * kH * 2);
    u16* y_c    = (u16*)alloc((size_t)kN * kH * 2);
    u16* efs    = (u16*)alloc((size_t)kE * 64 * 2);
    u16* tm1 = (u16*)alloc((size_t)kL * 768 * 256 * 2);
    u16* tm2 = (u16*)alloc((size_t)kL * 256 * 256 * 2);
    u16* tu1 = (u16*)alloc((size_t)kL * 512 * 256 * 2);
    u16* tu2 = (u16*)alloc((size_t)kL * 256 * 256 * 2);
    u16* tmc = (u16*)alloc((size_t)kL * 64 * 256 * 2);
    float* b1p = (float*)alloc((size_t)kL * 256 * 4);
    int* ei32 = (int*)alloc((size_t)2 * kE * 4);
    int* ba32 = (int*)alloc((size_t)kN * 4);
    int* cnt  = (int*)alloc((size_t)kN * 4);
    int* cur  = (int*)alloc((size_t)kN * 4);
    int* rank = (int*)alloc((size_t)kE * 4);
    int* ssorted = (int*)alloc((size_t)kE * 4);
    int* dsorted = (int*)alloc((size_t)kE * 4);
    int* flag = (int*)alloc(4);

    k_detect_i64<<<1, 64, 0, stream>>>((const unsigned*)ei_raw, flag);
    k_cvt_idx<<<(2 * kE + 255) / 256, 256, 0, stream>>>((const unsigned*)ei_raw, flag, ei32, 2 * kE);
    k_cvt_idx<<<(kN + 255) / 256, 256, 0, stream>>>((const unsigned*)ba_raw, flag, ba32, kN);
    const int* src = ei32;
    const int* dst = ei32 + kE;

    hipMemsetAsync(cnt, 0, (size_t)kN * 4, stream);
    k_hist<<<(kE + 255) / 256, 256, 0, stream>>>(dst, cnt);
    k_scan<<<1, 256, 0, stream>>>(cnt, cur);
    k_scatter<<<(kE + 255) / 256, 256, 0, stream>>>(src, dst, cur, rank, ssorted, dsorted);

    const int prep_elems = kL * (768 + 256 + 512 + 256) * 256;
    k_prep_w<<<(prep_elems + 255) / 256, 256, 0, stream>>>(
        msg_W1, msg_W2, upd_W1, upd_W2, tm1, tm2, tu1, tu2);
    k_prep_m<<<dim3(kL, 4), 256, 0, stream>>>(edge_W, edge_b, msg_W1, msg_b1, tmc, b1p);
    k_prep_ef<<<(kE * 64 + 255) / 256, 256, 0, stream>>>(ef, rank, efs);

    k_encode_nodes<<<kN / 4, 256, 0, stream>>>(nf, node_W, node_b, x, x_bf);
    hipMemsetAsync(agg, 0, (size_t)kN * kH * sizeof(float), stream);
    hipMemsetAsync(pooled, 0, (size_t)kB * kH * sizeof(float), stream);

    for (int l = 0; l < kL; ++l) {
        k_node_pre<<<dim3((kN + 63) / 64, 3), 256, 0, stream>>>(
            x_bf, tm1 + (size_t)l * 768 * 256, tu1 + (size_t)l * 512 * 256,
            y_a, y_b, y_c);
        k_msg<<<kE / 64, 256, 0, stream>>>(efs, ssorted, dsorted, y_a, y_b,
            tmc + (size_t)l * 64 * 256, b1p + l * 256,
            tm2 + (size_t)l * 256 * 256, msg_b2 + l * kH, agg);
        k_upd<<<(kN + 31) / 32, 256, 0, stream>>>(x, x_bf, agg,
            tu1 + (size_t)l * 512 * 256 + 8 * 8192, upd_b1 + l * kH,
            tu2 + (size_t)l * 256 * 256, upd_b2 + l * kH,
            ln_g + l * kH, ln_b + l * kH, y_c);
    }

    k_pool_part<<<kB * 4, 256, 0, stream>>>(x, ba32, pooled);
    k_ro<<<kB, 256, 0, stream>>>(pooled, ba32, ro_W1, ro_b1, ro_W2, ro_b2, (float*)d_out);
}